// Round 4
// baseline (367.450 us; speedup 1.0000x reference)
//
#include <hip/hip_runtime.h>

#define VOCAB   8
#define HIDDEN  768
#define DINUC   192
#define CONCAT  960
#define NDID    17               // 16 dinuc ids + 1 "no dinuc" (last position)
#define NROWS   (VOCAB * NDID)   // 136 distinct output rows
#define SEQ     2048
#define BATCH   32
#define LN_EPS  1e-12f

typedef float v4f __attribute__((ext_vector_type(4)));  // native vec for nontemporal

// ---------------------------------------------------------------------------
// K1 (fused): table[row=(id*17+did)][:] = LN( [tok[id]|din[did]|0] @ W^T + b )
// One block (256 thr = 4 waves) per row.
//  Phase A: stage e = concat embedding (960 f) in LDS; each lane hoists its
//           15 reusable e-values into 4 float4 registers.
//  Phase B: each wave computes 192 dots; W row read coalesced (64 lanes x
//           float4 contiguous), 6-step shfl_xor reduction, result -> LDS.
//  Phase C: two-pass LayerNorm over x[768] in LDS, write row to table.
// ---------------------------------------------------------------------------
__global__ __launch_bounds__(256) void k_table(
    const float* __restrict__ tok, const float* __restrict__ din,
    const float* __restrict__ W, const float* __restrict__ bias,
    const float* __restrict__ gamma, const float* __restrict__ beta,
    float* __restrict__ table) {
    int row = blockIdx.x;          // 0..135
    int id  = row / NDID;
    int did = row - id * NDID;

    __shared__ float e[CONCAT];
    __shared__ float x[HIDDEN];
    __shared__ float red[4];

    int tid = threadIdx.x;

    // Phase A: stage concat embedding
    for (int i = tid; i < HIDDEN; i += 256) e[i] = tok[id * HIDDEN + i];
    if (tid < DINUC) e[HIDDEN + tid] = (did < 16) ? din[did * DINUC + tid] : 0.f;
    __syncthreads();

    int wave = tid >> 6;
    int lane = tid & 63;
    const float4* e4 = (const float4*)e;
    float4 er0 = e4[lane];
    float4 er1 = e4[64 + lane];
    float4 er2 = e4[128 + lane];
    float4 er3 = (lane < 48) ? e4[192 + lane] : make_float4(0.f, 0.f, 0.f, 0.f);

    // Phase B: 192 dots per wave, coalesced W reads
    #pragma unroll 2
    for (int i = 0; i < HIDDEN / 4; ++i) {
        int o = wave * (HIDDEN / 4) + i;
        const float4* w4 = (const float4*)(W + (size_t)o * CONCAT);
        float4 a0 = w4[lane];
        float4 a1 = w4[64 + lane];
        float4 a2 = w4[128 + lane];
        float4 a3 = (lane < 48) ? w4[192 + lane] : make_float4(0.f, 0.f, 0.f, 0.f);
        float acc = er0.x * a0.x + er0.y * a0.y + er0.z * a0.z + er0.w * a0.w
                  + er1.x * a1.x + er1.y * a1.y + er1.z * a1.z + er1.w * a1.w
                  + er2.x * a2.x + er2.y * a2.y + er2.z * a2.z + er2.w * a2.w
                  + er3.x * a3.x + er3.y * a3.y + er3.z * a3.z + er3.w * a3.w;
        #pragma unroll
        for (int m = 32; m; m >>= 1) acc += __shfl_xor(acc, m, 64);
        if (lane == 0) x[o] = acc;
    }
    __syncthreads();

    // Phase C: LayerNorm (two-pass, exact)
    float v[3];
    float s = 0.f;
    #pragma unroll
    for (int k = 0; k < 3; ++k) {
        int o = tid + k * 256;
        float t = x[o] + bias[o];
        v[k] = t;
        s += t;
    }
    {   // block reduce: sum
        #pragma unroll
        for (int off = 32; off; off >>= 1) s += __shfl_down(s, off, 64);
        if (lane == 0) red[wave] = s;
        __syncthreads();
        s = red[0] + red[1] + red[2] + red[3];
        __syncthreads();
    }
    float mu = s * (1.f / HIDDEN);

    float sq = 0.f;
    #pragma unroll
    for (int k = 0; k < 3; ++k) {
        float d = v[k] - mu;
        sq += d * d;
    }
    {   // block reduce: sumsq
        #pragma unroll
        for (int off = 32; off; off >>= 1) sq += __shfl_down(sq, off, 64);
        if (lane == 0) red[wave] = sq;
        __syncthreads();
        sq = red[0] + red[1] + red[2] + red[3];
        __syncthreads();
    }
    float rstd = rsqrtf(sq * (1.f / HIDDEN) + LN_EPS);

    #pragma unroll
    for (int k = 0; k < 3; ++k) {
        int o = tid + k * 256;
        table[row * HIDDEN + o] = (v[k] - mu) * rstd * gamma[o] + beta[o];
    }
}

// ---------------------------------------------------------------------------
// K2: broadcast. out[b,s,:] = table[id*17+did]. One float4 per thread.
// block = (192, 4): 4 rows per block, 192 float4 per row. 16384 blocks.
// Non-temporal stores: pure 201 MB write stream, don't allocate in L2.
// ---------------------------------------------------------------------------
__global__ __launch_bounds__(768) void k_bcast(
    const int* __restrict__ ids,
    const float* __restrict__ table,
    v4f* __restrict__ out) {
    int row = blockIdx.x * 4 + threadIdx.y;     // 0 .. 65535 (= b*SEQ + s)
    int s   = row & (SEQ - 1);
    int a   = ids[row];
    int did;
    if (s == SEQ - 1) {
        did = 16;                               // padded position: no dinuc
    } else {
        int b = ids[row + 1];
        bool valid = (a >= 4) & (a <= 7) & (b >= 4) & (b <= 7);
        did = valid ? ((a - 4) * 4 + (b - 4)) : 0;
    }
    const v4f* src = (const v4f*)(table + (a * NDID + did) * HIDDEN);
    v4f val = src[threadIdx.x];
    __builtin_nontemporal_store(val, &out[(size_t)row * (HIDDEN / 4) + threadIdx.x]);
}

// ---------------------------------------------------------------------------
extern "C" void kernel_launch(void* const* d_in, const int* in_sizes, int n_in,
                              void* d_out, int out_size, void* d_ws, size_t ws_size,
                              hipStream_t stream) {
    const int*   ids   = (const int*)d_in[0];
    const float* tok   = (const float*)d_in[1];
    const float* din   = (const float*)d_in[2];
    const float* W     = (const float*)d_in[3];
    const float* bias  = (const float*)d_in[4];
    const float* gamma = (const float*)d_in[5];
    const float* beta  = (const float*)d_in[6];

    float* table = (float*)d_ws;                 // 136*768 floats = 417792 B

    k_table<<<NROWS, 256, 0, stream>>>(tok, din, W, bias, gamma, beta, table);
    k_bcast<<<(BATCH * SEQ) / 4, dim3(192, 4), 0, stream>>>(ids, table, (v4f*)d_out);
}

// Round 5
// 240.573 us; speedup vs baseline: 1.5274x; 1.5274x over previous
//
#include <hip/hip_runtime.h>

#define VOCAB   8
#define HIDDEN  768
#define DINUC   192
#define CONCAT  960
#define NDID    17               // 16 dinuc ids + 1 "no dinuc" (last position)
#define NROWS   (VOCAB * NDID)   // 136 distinct output rows
#define SEQ     2048
#define BATCH   32
#define LN_EPS  1e-12f

typedef float v4f __attribute__((ext_vector_type(4)));  // native vec for nontemporal

// ---------------------------------------------------------------------------
// K1: one WAVE per dot product (coalesced W reads + 6-step shuffle reduce).
//   TD[r][o], r in [0,8):   tok[r](768) . W[o][0:768]
//   TD[r][o], r in [8,24):  din[r-8](192) . W[o][768:960]
// 24*768 = 18432 waves = 4608 blocks x 256 thr. W row read as 64 lanes x
// float4 contiguous (1 KB/inst). Plenty of TLP (~18 waves/SIMD) to hide
// L2 latency — the round-4 failure mode (136 blocks, serial chains) is gone.
// ---------------------------------------------------------------------------
__global__ __launch_bounds__(256) void k_td(
    const float* __restrict__ tok, const float* __restrict__ din,
    const float* __restrict__ W, float* __restrict__ TD) {
    int w    = (blockIdx.x * 256 + threadIdx.x) >> 6;   // wave id: 0..18431
    int lane = threadIdx.x & 63;
    int r    = w / HIDDEN;                              // 0..23 (wave-uniform)
    int o    = w - r * HIDDEN;                          // 0..767

    float acc = 0.f;
    if (r < VOCAB) {
        const float4* e4 = (const float4*)(tok + r * HIDDEN);
        const float4* w4 = (const float4*)(W + (size_t)o * CONCAT);
        #pragma unroll
        for (int k = 0; k < 3; ++k) {                   // 3 * 64 * 4 = 768
            float4 a = w4[k * 64 + lane];
            float4 b = e4[k * 64 + lane];
            acc += a.x * b.x + a.y * b.y + a.z * b.z + a.w * b.w;
        }
    } else {
        if (lane < 48) {                                // 48 * 4 = 192
            const float4* e4 = (const float4*)(din + (r - VOCAB) * DINUC);
            const float4* w4 = (const float4*)(W + (size_t)o * CONCAT + HIDDEN);
            float4 a = w4[lane];
            float4 b = e4[lane];
            acc = a.x * b.x + a.y * b.y + a.z * b.z + a.w * b.w;
        }
    }
    #pragma unroll
    for (int m = 32; m; m >>= 1) acc += __shfl_xor(acc, m, 64);
    if (lane == 0) TD[w] = acc;
}

// ---------------------------------------------------------------------------
// K2: table[row=(id*17+did)][o] = LN( T[id][o] + (did<16 ? D[did][o] : 0) + b[o] )
// One block (256 thr = 4 waves) per row; each thread owns 3 outputs.
// ---------------------------------------------------------------------------
__device__ inline float block_reduce_sum(float s, float* red) {
    int lane = threadIdx.x & 63;
    int wave = threadIdx.x >> 6;
    #pragma unroll
    for (int off = 32; off; off >>= 1) s += __shfl_down(s, off, 64);
    if (lane == 0) red[wave] = s;
    __syncthreads();
    float tot = red[0] + red[1] + red[2] + red[3];
    __syncthreads();
    return tot;
}

__global__ __launch_bounds__(256) void k_table(
    const float* __restrict__ TD, const float* __restrict__ bias,
    const float* __restrict__ gamma, const float* __restrict__ beta,
    float* __restrict__ table) {
    int row = blockIdx.x;          // 0..135
    int id  = row / NDID;
    int did = row - id * NDID;
    const float* T = TD + id * HIDDEN;
    const float* D = TD + (VOCAB + did) * HIDDEN;
    bool hasd = (did < 16);

    __shared__ float red[4];
    int tid = threadIdx.x;

    float v[3];
    float s = 0.f;
    #pragma unroll
    for (int k = 0; k < 3; ++k) {
        int o = tid + k * 256;
        float x = T[o] + bias[o];
        if (hasd) x += D[o];
        v[k] = x;
        s += x;
    }
    float mu = block_reduce_sum(s, red) * (1.f / HIDDEN);

    float sq = 0.f;
    #pragma unroll
    for (int k = 0; k < 3; ++k) {
        float d = v[k] - mu;
        sq += d * d;
    }
    float var = block_reduce_sum(sq, red) * (1.f / HIDDEN);
    float rstd = rsqrtf(var + LN_EPS);

    #pragma unroll
    for (int k = 0; k < 3; ++k) {
        int o = tid + k * 256;
        table[row * HIDDEN + o] = (v[k] - mu) * rstd * gamma[o] + beta[o];
    }
}

// ---------------------------------------------------------------------------
// K3: broadcast. out[b,s,:] = table[id*17+did]. One float4 per thread.
// block = (192, 4): 4 rows per block, 192 float4 per row. 16384 blocks.
// Non-temporal stores: pure 201 MB write stream, don't allocate in L2.
// ---------------------------------------------------------------------------
__global__ __launch_bounds__(768) void k_bcast(
    const int* __restrict__ ids,
    const float* __restrict__ table,
    v4f* __restrict__ out) {
    int row = blockIdx.x * 4 + threadIdx.y;     // 0 .. 65535 (= b*SEQ + s)
    int s   = row & (SEQ - 1);
    int a   = ids[row];
    int did;
    if (s == SEQ - 1) {
        did = 16;                               // padded position: no dinuc
    } else {
        int b = ids[row + 1];
        bool valid = (a >= 4) & (a <= 7) & (b >= 4) & (b <= 7);
        did = valid ? ((a - 4) * 4 + (b - 4)) : 0;
    }
    const v4f* src = (const v4f*)(table + (a * NDID + did) * HIDDEN);
    v4f val = src[threadIdx.x];
    __builtin_nontemporal_store(val, &out[(size_t)row * (HIDDEN / 4) + threadIdx.x]);
}

// ---------------------------------------------------------------------------
extern "C" void kernel_launch(void* const* d_in, const int* in_sizes, int n_in,
                              void* d_out, int out_size, void* d_ws, size_t ws_size,
                              hipStream_t stream) {
    const int*   ids   = (const int*)d_in[0];
    const float* tok   = (const float*)d_in[1];
    const float* din   = (const float*)d_in[2];
    const float* W     = (const float*)d_in[3];
    const float* bias  = (const float*)d_in[4];
    const float* gamma = (const float*)d_in[5];
    const float* beta  = (const float*)d_in[6];

    float* table = (float*)d_ws;                 // 136*768 floats = 417792 B
    float* TD    = table + NROWS * HIDDEN;       //  24*768 floats =  73728 B

    k_td   <<<(24 * HIDDEN) / 4, 256, 0, stream>>>(tok, din, W, TD);
    k_table<<<NROWS, 256, 0, stream>>>(TD, bias, gamma, beta, table);
    k_bcast<<<(BATCH * SEQ) / 4, dim3(192, 4), 0, stream>>>(ids, table, (v4f*)d_out);
}